// Round 6
// baseline (240.056 us; speedup 1.0000x reference)
//
#include <hip/hip_runtime.h>

#define NB 32
#define NS 2048
#define NE 8
// softmax scale 1/sqrt(d_k)=0.5 folded with log2(e) so we can use v_exp_f32 (2^x)
#define QSCALE 0.72134752044448170367f

typedef float v2f __attribute__((ext_vector_type(2)));
typedef float v4f __attribute__((ext_vector_type(4)));

// Packed f32 math via native vector ops -> LLVM selects v_pk_{mul,fma,add}_f32
// on gfx90a+ with correct op_sel/op_sel_hi (no hand-asm modifier footguns).
__device__ __forceinline__ v2f pkfma(v2f a, v2f b, v2f c) {
  return __builtin_elementwise_fma(a, b, c);
}

// ---------------------------------------------------------------------------
// Kernel A: per (b, q-chunk, k-slice) partial attention, packed-f32 math,
// with fused split-K finalize (atomic ticket; last block of each
// (b,q-chunk) group sums the NSLICE partials, normalizes, projects, stores).
//   h = cos(x + theta); scores bounded in [-2,2] -> no max pass needed.
//   LDS k-rows are HEAD-INTERLEAVED so head0/head1 ride the lo/hi halves of
//   v_pk_* ops: per (q,k,both heads) = 9 pk + 2 exp slots. One LDS row read
//   is reused for QPT=4 queries -> LDS pipe well below VALU demand.
// FUSED=true (single slice) skips partials/ticket entirely.
// ---------------------------------------------------------------------------
template <int KSLICE, int QPT, bool FUSED>
__global__ __launch_bounds__(256) void attn_part_kernel(
    const float* __restrict__ x, const float* __restrict__ theta,
    const float* __restrict__ Wout, float* __restrict__ part,
    int* __restrict__ cnt, float* __restrict__ outp) {
  constexpr int NSLICE = NS / KSLICE;
  __shared__ float kv[KSLICE * 8];
  __shared__ int lastFlag;

  const int b = blockIdx.z;
  const int slice = blockIdx.y;
  const int qbase = blockIdx.x * (256 * QPT) + threadIdx.x;  // +256*g per query
  const int k0 = slice * KSLICE;

  float th[8];
#pragma unroll
  for (int e = 0; e < 8; ++e) th[e] = theta[e];

  // Stage the k-slice of h into LDS, head-interleaved per row.
  for (int r = threadIdx.x; r < KSLICE; r += 256) {
    const float4* xr = (const float4*)(x + ((size_t)b * NS + k0 + r) * 8);
    float4 lo = xr[0], hi = xr[1];
    lo.x = __cosf(lo.x + th[0]);
    lo.y = __cosf(lo.y + th[1]);
    lo.z = __cosf(lo.z + th[2]);
    lo.w = __cosf(lo.w + th[3]);
    hi.x = __cosf(hi.x + th[4]);
    hi.y = __cosf(hi.y + th[5]);
    hi.z = __cosf(hi.z + th[6]);
    hi.w = __cosf(hi.w + th[7]);
    // interleave: (k0,k4,k1,k5) (k2,k6,k3,k7)
    ((float4*)kv)[2 * r] = make_float4(lo.x, hi.x, lo.y, hi.y);
    ((float4*)kv)[2 * r + 1] = make_float4(lo.z, hi.z, lo.w, hi.w);
  }

  // This thread's QPT query rows as head-interleaved pairs, pre-scaled.
  v2f qp[QPT][4];
#pragma unroll
  for (int g = 0; g < QPT; ++g) {
    const float4* xq = (const float4*)(x + ((size_t)b * NS + qbase + 256 * g) * 8);
    float4 lo = xq[0], hi = xq[1];
    qp[g][0] = (v2f){__cosf(lo.x + th[0]) * QSCALE, __cosf(hi.x + th[4]) * QSCALE};
    qp[g][1] = (v2f){__cosf(lo.y + th[1]) * QSCALE, __cosf(hi.y + th[5]) * QSCALE};
    qp[g][2] = (v2f){__cosf(lo.z + th[2]) * QSCALE, __cosf(hi.z + th[6]) * QSCALE};
    qp[g][3] = (v2f){__cosf(lo.w + th[3]) * QSCALE, __cosf(hi.w + th[7]) * QSCALE};
  }

  __syncthreads();

  v2f acc[QPT][4];  // acc[g][i] = (sum p0*k_i, sum p1*k_{4+i})
  v2f den[QPT];     // (sum p0, sum p1)
#pragma unroll
  for (int g = 0; g < QPT; ++g) {
    acc[g][0] = (v2f){0.f, 0.f};
    acc[g][1] = (v2f){0.f, 0.f};
    acc[g][2] = (v2f){0.f, 0.f};
    acc[g][3] = (v2f){0.f, 0.f};
    den[g] = (v2f){0.f, 0.f};
  }

  const v4f* kp = (const v4f*)kv;
#pragma unroll 2
  for (int j = 0; j < KSLICE; ++j) {
    // Broadcast LDS reads (all lanes same row) -> conflict-free b128 x2.
    v4f A = kp[2 * j];
    v4f Bv = kp[2 * j + 1];
    v2f kk0 = A.xy;   // (k0, k4)
    v2f kk1 = A.zw;   // (k1, k5)
    v2f kk2 = Bv.xy;  // (k2, k6)
    v2f kk3 = Bv.zw;  // (k3, k7)
#pragma unroll
    for (int g = 0; g < QPT; ++g) {
      v2f s = qp[g][0] * kk0;
      s = pkfma(qp[g][1], kk1, s);
      s = pkfma(qp[g][2], kk2, s);
      s = pkfma(qp[g][3], kk3, s);
      v2f P;
      P.x = __builtin_amdgcn_exp2f(s.x);  // v_exp_f32
      P.y = __builtin_amdgcn_exp2f(s.y);
      acc[g][0] = pkfma(P, kk0, acc[g][0]);
      acc[g][1] = pkfma(P, kk1, acc[g][1]);
      acc[g][2] = pkfma(P, kk2, acc[g][2]);
      acc[g][3] = pkfma(P, kk3, acc[g][3]);
      den[g] = den[g] + P;
    }
  }

  if (FUSED) {
#pragma unroll
    for (int g = 0; g < QPT; ++g) {
      const int q = qbase + 256 * g;
      const float i0 = 1.0f / den[g].x, i1 = 1.0f / den[g].y;
      float m[8] = {acc[g][0].x * i0, acc[g][1].x * i0, acc[g][2].x * i0,
                    acc[g][3].x * i0, acc[g][0].y * i1, acc[g][1].y * i1,
                    acc[g][2].y * i1, acc[g][3].y * i1};
      float o[8];
#pragma unroll
      for (int e = 0; e < 8; ++e) {
        float s = 0.f;
#pragma unroll
        for (int f = 0; f < 8; ++f) s += m[f] * Wout[e * 8 + f];
        o[e] = s;
      }
      float4* op = (float4*)(outp + ((size_t)b * NS + q) * 8);
      op[0] = make_float4(o[0], o[1], o[2], o[3]);
      op[1] = make_float4(o[4], o[5], o[6], o[7]);
    }
    return;
  }

  // ---- store partials: [slice][component(10)][B*S]  (coalesced) ----
#pragma unroll
  for (int g = 0; g < QPT; ++g) {
    const int idx = b * NS + qbase + 256 * g;
    float* p = part + (size_t)slice * 10 * (NB * NS) + idx;
    p[0 * (NB * NS)] = acc[g][0].x;
    p[1 * (NB * NS)] = acc[g][1].x;
    p[2 * (NB * NS)] = acc[g][2].x;
    p[3 * (NB * NS)] = acc[g][3].x;
    p[4 * (NB * NS)] = acc[g][0].y;
    p[5 * (NB * NS)] = acc[g][1].y;
    p[6 * (NB * NS)] = acc[g][2].y;
    p[7 * (NB * NS)] = acc[g][3].y;
    p[8 * (NB * NS)] = den[g].x;
    p[9 * (NB * NS)] = den[g].y;
  }

  // ---- atomic ticket: last block of this (b, q-chunk) group finalizes ----
  __threadfence();  // release partial stores to device scope
  if (threadIdx.x == 0) {
    const int group = b * gridDim.x + blockIdx.x;
    int old = __hip_atomic_fetch_add(&cnt[group], 1, __ATOMIC_ACQ_REL,
                                     __HIP_MEMORY_SCOPE_AGENT);
    lastFlag = (old == NSLICE - 1);
  }
  __syncthreads();
  if (!lastFlag) return;
  __threadfence();  // acquire: see all groups' partial stores

#pragma unroll
  for (int g = 0; g < QPT; ++g) {
    const int idx = b * NS + qbase + 256 * g;
    float a[10];
#pragma unroll
    for (int c = 0; c < 10; ++c) a[c] = 0.f;
    for (int sl = 0; sl < NSLICE; ++sl) {
      const float* p = part + (size_t)sl * 10 * (NB * NS) + idx;
#pragma unroll
      for (int c = 0; c < 10; ++c) a[c] += p[c * (NB * NS)];
    }
    const float i0 = 1.0f / a[8], i1 = 1.0f / a[9];
    float m[8] = {a[0] * i0, a[1] * i0, a[2] * i0, a[3] * i0,
                  a[4] * i1, a[5] * i1, a[6] * i1, a[7] * i1};
    float o[8];
#pragma unroll
    for (int e = 0; e < 8; ++e) {
      float s = 0.f;
#pragma unroll
      for (int f = 0; f < 8; ++f) s += m[f] * Wout[e * 8 + f];
      o[e] = s;
    }
    float4* op = (float4*)(outp + (size_t)idx * 8);
    op[0] = make_float4(o[0], o[1], o[2], o[3]);
    op[1] = make_float4(o[4], o[5], o[6], o[7]);
  }
}

extern "C" void kernel_launch(void* const* d_in, const int* in_sizes, int n_in,
                              void* d_out, int out_size, void* d_ws,
                              size_t ws_size, hipStream_t stream) {
  const float* x = (const float*)d_in[0];      // [32, 2048, 8]
  const float* theta = (const float*)d_in[1];  // [8]
  const float* W = (const float*)d_in[2];      // [8, 8]
  float* out = (float*)d_out;                  // [32, 2048, 8]
  float* ws = (float*)d_ws;

  const size_t per_slice = (size_t)NB * NS * 10 * sizeof(float);  // 2.62 MB
  const int ngroups = NB * (NS / 1024);                           // 64

  if (ws_size >= 8 * per_slice + ngroups * sizeof(int)) {
    // 8-way split-K, 4 queries/thread, fused finalize via atomic ticket.
    int* cnt = (int*)((char*)ws + 8 * per_slice);
    hipMemsetAsync(cnt, 0, ngroups * sizeof(int), stream);
    attn_part_kernel<256, 4, false>
        <<<dim3(NS / 1024, 8, NB), 256, 0, stream>>>(x, theta, W, ws, cnt, out);
  } else {
    // Fused single-pass fallback (64 KB LDS, no workspace needed).
    attn_part_kernel<2048, 2, true>
        <<<dim3(NS / 512, 1, NB), 256, 0, stream>>>(x, theta, W, out, nullptr,
                                                    out);
  }
}

// Round 7
// 132.229 us; speedup vs baseline: 1.8155x; 1.8155x over previous
//
#include <hip/hip_runtime.h>

#define NB 32
#define NS 2048
#define NE 8
// softmax scale 1/sqrt(d_k)=0.5 folded with log2(e) so we can use v_exp_f32 (2^x)
#define QSCALE 0.72134752044448170367f

typedef float v2f __attribute__((ext_vector_type(2)));
typedef float v4f __attribute__((ext_vector_type(4)));

// Packed f32 math via native vector ops -> LLVM selects v_pk_{mul,fma,add}_f32
// on gfx90a+ with correct op_sel/op_sel_hi (no hand-asm modifier footguns).
__device__ __forceinline__ v2f pkfma(v2f a, v2f b, v2f c) {
  return __builtin_elementwise_fma(a, b, c);
}

// ---------------------------------------------------------------------------
// Kernel A: per (b, q-chunk, k-slice) partial attention, packed-f32 math.
//   h = cos(x + theta); scores bounded in [-2,2] -> no max pass needed.
//   LDS stores each k-row HEAD-INTERLEAVED: (k0,k4),(k1,k5),(k2,k6),(k3,k7)
//   so head0/head1 run in the lo/hi halves of v_pk_* instructions:
//   per (q,k,both heads): 4 pk (dot) + 2 exp + 4 pk_fma + 1 pk_add = 11 slots.
//   One LDS row read is reused for QPT=4 queries -> LDS pipe at ~half of
//   VALU demand (QPT=2 left them co-saturated: R5 VALUBusy=66%).
// FUSED=true (single slice) normalizes + projects + writes out directly.
// ---------------------------------------------------------------------------
template <int KSLICE, int QPT, bool FUSED>
__global__ __launch_bounds__(256) void attn_part_kernel(
    const float* __restrict__ x, const float* __restrict__ theta,
    const float* __restrict__ Wout, float* __restrict__ outp) {
  __shared__ float kv[KSLICE * 8];

  const int b = blockIdx.z;
  const int slice = blockIdx.y;
  const int qbase = blockIdx.x * (256 * QPT) + threadIdx.x;  // +256*g per query
  const int k0 = slice * KSLICE;

  float th[8];
#pragma unroll
  for (int e = 0; e < 8; ++e) th[e] = theta[e];

  // Stage the k-slice of h into LDS, head-interleaved per row.
  for (int r = threadIdx.x; r < KSLICE; r += 256) {
    const float4* xr = (const float4*)(x + ((size_t)b * NS + k0 + r) * 8);
    float4 lo = xr[0], hi = xr[1];
    lo.x = __cosf(lo.x + th[0]);
    lo.y = __cosf(lo.y + th[1]);
    lo.z = __cosf(lo.z + th[2]);
    lo.w = __cosf(lo.w + th[3]);
    hi.x = __cosf(hi.x + th[4]);
    hi.y = __cosf(hi.y + th[5]);
    hi.z = __cosf(hi.z + th[6]);
    hi.w = __cosf(hi.w + th[7]);
    // interleave: (k0,k4,k1,k5) (k2,k6,k3,k7)
    ((float4*)kv)[2 * r] = make_float4(lo.x, hi.x, lo.y, hi.y);
    ((float4*)kv)[2 * r + 1] = make_float4(lo.z, hi.z, lo.w, hi.w);
  }

  // This thread's QPT query rows as head-interleaved pairs, pre-scaled.
  v2f qp[QPT][4];
#pragma unroll
  for (int g = 0; g < QPT; ++g) {
    const float4* xq = (const float4*)(x + ((size_t)b * NS + qbase + 256 * g) * 8);
    float4 lo = xq[0], hi = xq[1];
    qp[g][0] = (v2f){__cosf(lo.x + th[0]) * QSCALE, __cosf(hi.x + th[4]) * QSCALE};
    qp[g][1] = (v2f){__cosf(lo.y + th[1]) * QSCALE, __cosf(hi.y + th[5]) * QSCALE};
    qp[g][2] = (v2f){__cosf(lo.z + th[2]) * QSCALE, __cosf(hi.z + th[6]) * QSCALE};
    qp[g][3] = (v2f){__cosf(lo.w + th[3]) * QSCALE, __cosf(hi.w + th[7]) * QSCALE};
  }

  __syncthreads();

  v2f acc[QPT][4];  // acc[g][i] = (sum p0*k_i, sum p1*k_{4+i})
  v2f den[QPT];     // (sum p0, sum p1)
#pragma unroll
  for (int g = 0; g < QPT; ++g) {
    acc[g][0] = (v2f){0.f, 0.f};
    acc[g][1] = (v2f){0.f, 0.f};
    acc[g][2] = (v2f){0.f, 0.f};
    acc[g][3] = (v2f){0.f, 0.f};
    den[g] = (v2f){0.f, 0.f};
  }

  const v4f* kp = (const v4f*)kv;
#pragma unroll 4
  for (int j = 0; j < KSLICE; ++j) {
    // Broadcast LDS reads (all lanes same row) -> conflict-free b128 x2.
    v4f A = kp[2 * j];
    v4f Bv = kp[2 * j + 1];
    v2f kk0 = A.xy;   // (k0, k4)
    v2f kk1 = A.zw;   // (k1, k5)
    v2f kk2 = Bv.xy;  // (k2, k6)
    v2f kk3 = Bv.zw;  // (k3, k7)
#pragma unroll
    for (int g = 0; g < QPT; ++g) {
      v2f s = qp[g][0] * kk0;
      s = pkfma(qp[g][1], kk1, s);
      s = pkfma(qp[g][2], kk2, s);
      s = pkfma(qp[g][3], kk3, s);
      v2f P;
      P.x = __builtin_amdgcn_exp2f(s.x);  // v_exp_f32
      P.y = __builtin_amdgcn_exp2f(s.y);
      acc[g][0] = pkfma(P, kk0, acc[g][0]);
      acc[g][1] = pkfma(P, kk1, acc[g][1]);
      acc[g][2] = pkfma(P, kk2, acc[g][2]);
      acc[g][3] = pkfma(P, kk3, acc[g][3]);
      den[g] = den[g] + P;
    }
  }

#pragma unroll
  for (int g = 0; g < QPT; ++g) {
    const int q = qbase + 256 * g;
    if (FUSED) {
      const float i0 = 1.0f / den[g].x, i1 = 1.0f / den[g].y;
      float m[8] = {acc[g][0].x * i0, acc[g][1].x * i0, acc[g][2].x * i0,
                    acc[g][3].x * i0, acc[g][0].y * i1, acc[g][1].y * i1,
                    acc[g][2].y * i1, acc[g][3].y * i1};
      float o[8];
#pragma unroll
      for (int e = 0; e < 8; ++e) {
        float s = 0.f;
#pragma unroll
        for (int f = 0; f < 8; ++f) s += m[f] * Wout[e * 8 + f];
        o[e] = s;
      }
      float4* op = (float4*)(outp + ((size_t)b * NS + q) * 8);
      op[0] = make_float4(o[0], o[1], o[2], o[3]);
      op[1] = make_float4(o[4], o[5], o[6], o[7]);
    } else {
      // partial layout: [slice][component(10)][B*S]  (coalesced stores)
      const int idx = b * NS + q;
      float* p = outp + (size_t)slice * 10 * (NB * NS) + idx;
      p[0 * (NB * NS)] = acc[g][0].x;
      p[1 * (NB * NS)] = acc[g][1].x;
      p[2 * (NB * NS)] = acc[g][2].x;
      p[3 * (NB * NS)] = acc[g][3].x;
      p[4 * (NB * NS)] = acc[g][0].y;
      p[5 * (NB * NS)] = acc[g][1].y;
      p[6 * (NB * NS)] = acc[g][2].y;
      p[7 * (NB * NS)] = acc[g][3].y;
      p[8 * (NB * NS)] = den[g].x;
      p[9 * (NB * NS)] = den[g].y;
    }
  }
}

// ---------------------------------------------------------------------------
// Kernel B: sum slice partials, normalize, apply W_out^T, write out.
// ---------------------------------------------------------------------------
__global__ __launch_bounds__(256) void attn_reduce_kernel(
    const float* __restrict__ part, const float* __restrict__ Wout,
    float* __restrict__ out, int nslice) {
  const int idx = blockIdx.x * 256 + threadIdx.x;  // 0 .. B*S-1
  float a[10];
#pragma unroll
  for (int c = 0; c < 10; ++c) a[c] = 0.f;
  for (int sl = 0; sl < nslice; ++sl) {
    const float* p = part + (size_t)sl * 10 * (NB * NS) + idx;
#pragma unroll
    for (int c = 0; c < 10; ++c) a[c] += p[c * (NB * NS)];
  }
  const float i0 = 1.0f / a[8], i1 = 1.0f / a[9];
  float m[8] = {a[0] * i0, a[1] * i0, a[2] * i0, a[3] * i0,
                a[4] * i1, a[5] * i1, a[6] * i1, a[7] * i1};
  float o[8];
#pragma unroll
  for (int e = 0; e < 8; ++e) {
    float s = 0.f;
#pragma unroll
    for (int f = 0; f < 8; ++f) s += m[f] * Wout[e * 8 + f];
    o[e] = s;
  }
  float4* op = (float4*)(out + (size_t)idx * 8);
  op[0] = make_float4(o[0], o[1], o[2], o[3]);
  op[1] = make_float4(o[4], o[5], o[6], o[7]);
}

extern "C" void kernel_launch(void* const* d_in, const int* in_sizes, int n_in,
                              void* d_out, int out_size, void* d_ws,
                              size_t ws_size, hipStream_t stream) {
  const float* x = (const float*)d_in[0];      // [32, 2048, 8]
  const float* theta = (const float*)d_in[1];  // [8]
  const float* W = (const float*)d_in[2];      // [8, 8]
  float* out = (float*)d_out;                  // [32, 2048, 8]
  float* ws = (float*)d_ws;

  const size_t per_slice = (size_t)NB * NS * 10 * sizeof(float);  // 2.62 MB

  if (ws_size >= 8 * per_slice) {
    // 8-way split-K, 4 queries/thread: 512 blocks = 2/CU, 8 waves/CU.
    attn_part_kernel<256, 4, false>
        <<<dim3(NS / 1024, 8, NB), 256, 0, stream>>>(x, theta, W, ws);
    attn_reduce_kernel<<<(NB * NS) / 256, 256, 0, stream>>>(ws, W, out, 8);
  } else if (ws_size >= 4 * per_slice) {
    attn_part_kernel<512, 4, false>
        <<<dim3(NS / 1024, 4, NB), 256, 0, stream>>>(x, theta, W, ws);
    attn_reduce_kernel<<<(NB * NS) / 256, 256, 0, stream>>>(ws, W, out, 4);
  } else if (ws_size >= 2 * per_slice) {
    attn_part_kernel<1024, 4, false>
        <<<dim3(NS / 1024, 2, NB), 256, 0, stream>>>(x, theta, W, ws);
    attn_reduce_kernel<<<(NB * NS) / 256, 256, 0, stream>>>(ws, W, out, 2);
  } else {
    // Fused single-pass fallback (64 KB LDS, no workspace needed).
    attn_part_kernel<2048, 2, true>
        <<<dim3(NS / 512, 1, NB), 256, 0, stream>>>(x, theta, W, out);
  }
}

// Round 8
// 128.392 us; speedup vs baseline: 1.8697x; 1.0299x over previous
//
#include <hip/hip_runtime.h>

#define NB 32
#define NS 2048
#define NE 8
// softmax scale 1/sqrt(d_k)=0.5 folded with log2(e) so we can use v_exp_f32 (2^x)
#define QSCALE 0.72134752044448170367f

typedef float v2f __attribute__((ext_vector_type(2)));
typedef float v4f __attribute__((ext_vector_type(4)));

// Packed f32 math via native vector ops -> LLVM selects v_pk_{mul,fma,add}_f32
// on gfx90a+ with correct op_sel/op_sel_hi (no hand-asm modifier footguns).
__device__ __forceinline__ v2f pkfma(v2f a, v2f b, v2f c) {
  return __builtin_elementwise_fma(a, b, c);
}

// ---------------------------------------------------------------------------
// Kernel A: per (b, q-chunk, k-slice) partial attention, packed-f32 math,
// exp SOFTWARE-PIPELINED across k-iterations:
//   iteration j computes dot(j)+exp(j) but accumulates P(j-1)*kk(j-1), so the
//   trans-pipe latency of v_exp_f32 is hidden behind ~144 cycles of
//   independent pk issue instead of serializing dot->exp->acc per iteration.
//   h = cos(x + theta); scores bounded in [-2,2] -> no max pass needed.
//   LDS k-rows HEAD-INTERLEAVED: (k0,k4),(k1,k5),(k2,k6),(k3,k7) so both
//   heads ride lo/hi halves of v_pk_* ops. One LDS row read reused for QPT=4
//   queries.
// FUSED=true (single slice) normalizes + projects + writes out directly.
// ---------------------------------------------------------------------------
template <int KSLICE, int QPT, bool FUSED>
__global__ __launch_bounds__(256, 2) void attn_part_kernel(
    const float* __restrict__ x, const float* __restrict__ theta,
    const float* __restrict__ Wout, float* __restrict__ outp) {
  __shared__ float kv[KSLICE * 8];

  const int b = blockIdx.z;
  const int slice = blockIdx.y;
  const int qbase = blockIdx.x * (256 * QPT) + threadIdx.x;  // +256*g per query
  const int k0 = slice * KSLICE;

  float th[8];
#pragma unroll
  for (int e = 0; e < 8; ++e) th[e] = theta[e];

  // Stage the k-slice of h into LDS, head-interleaved per row.
  for (int r = threadIdx.x; r < KSLICE; r += 256) {
    const float4* xr = (const float4*)(x + ((size_t)b * NS + k0 + r) * 8);
    float4 lo = xr[0], hi = xr[1];
    lo.x = __cosf(lo.x + th[0]);
    lo.y = __cosf(lo.y + th[1]);
    lo.z = __cosf(lo.z + th[2]);
    lo.w = __cosf(lo.w + th[3]);
    hi.x = __cosf(hi.x + th[4]);
    hi.y = __cosf(hi.y + th[5]);
    hi.z = __cosf(hi.z + th[6]);
    hi.w = __cosf(hi.w + th[7]);
    // interleave: (k0,k4,k1,k5) (k2,k6,k3,k7)
    ((float4*)kv)[2 * r] = make_float4(lo.x, hi.x, lo.y, hi.y);
    ((float4*)kv)[2 * r + 1] = make_float4(lo.z, hi.z, lo.w, hi.w);
  }

  // This thread's QPT query rows as head-interleaved pairs, pre-scaled.
  v2f qp[QPT][4];
#pragma unroll
  for (int g = 0; g < QPT; ++g) {
    const float4* xq = (const float4*)(x + ((size_t)b * NS + qbase + 256 * g) * 8);
    float4 lo = xq[0], hi = xq[1];
    qp[g][0] = (v2f){__cosf(lo.x + th[0]) * QSCALE, __cosf(hi.x + th[4]) * QSCALE};
    qp[g][1] = (v2f){__cosf(lo.y + th[1]) * QSCALE, __cosf(hi.y + th[5]) * QSCALE};
    qp[g][2] = (v2f){__cosf(lo.z + th[2]) * QSCALE, __cosf(hi.z + th[6]) * QSCALE};
    qp[g][3] = (v2f){__cosf(lo.w + th[3]) * QSCALE, __cosf(hi.w + th[7]) * QSCALE};
  }

  __syncthreads();

  v2f acc[QPT][4];  // acc[g][i] = (sum p0*k_i, sum p1*k_{4+i})
  v2f den[QPT];     // (sum p0, sum p1)
#pragma unroll
  for (int g = 0; g < QPT; ++g) {
    acc[g][0] = (v2f){0.f, 0.f};
    acc[g][1] = (v2f){0.f, 0.f};
    acc[g][2] = (v2f){0.f, 0.f};
    acc[g][3] = (v2f){0.f, 0.f};
    den[g] = (v2f){0.f, 0.f};
  }

  const v4f* kp = (const v4f*)kv;

  // ---- pipeline prologue: dot+exp for j=0 ----
  v2f kkp[4];  // kk of the previous (not-yet-accumulated) iteration
  {
    v4f A = kp[0], Bv = kp[1];
    kkp[0] = A.xy;
    kkp[1] = A.zw;
    kkp[2] = Bv.xy;
    kkp[3] = Bv.zw;
  }
  v2f pP[QPT];  // exp results of the previous iteration
#pragma unroll
  for (int g = 0; g < QPT; ++g) {
    v2f s = qp[g][0] * kkp[0];
    s = pkfma(qp[g][1], kkp[1], s);
    s = pkfma(qp[g][2], kkp[2], s);
    s = pkfma(qp[g][3], kkp[3], s);
    pP[g].x = __builtin_amdgcn_exp2f(s.x);
    pP[g].y = __builtin_amdgcn_exp2f(s.y);
  }

#pragma unroll 4
  for (int j = 1; j < KSLICE; ++j) {
    // Broadcast LDS reads (all lanes same row) -> conflict-free b128 x2.
    v4f A = kp[2 * j];
    v4f Bv = kp[2 * j + 1];
    v2f kk0 = A.xy;   // (k0, k4)
    v2f kk1 = A.zw;   // (k1, k5)
    v2f kk2 = Bv.xy;  // (k2, k6)
    v2f kk3 = Bv.zw;  // (k3, k7)
    v2f P[QPT];
#pragma unroll
    for (int g = 0; g < QPT; ++g) {
      // dot for current j — independent of the accumulates below
      v2f s = qp[g][0] * kk0;
      s = pkfma(qp[g][1], kk1, s);
      s = pkfma(qp[g][2], kk2, s);
      s = pkfma(qp[g][3], kk3, s);
      // accumulate PREVIOUS iteration's P with previous kk (hides exp latency)
      acc[g][0] = pkfma(pP[g], kkp[0], acc[g][0]);
      acc[g][1] = pkfma(pP[g], kkp[1], acc[g][1]);
      acc[g][2] = pkfma(pP[g], kkp[2], acc[g][2]);
      acc[g][3] = pkfma(pP[g], kkp[3], acc[g][3]);
      den[g] = den[g] + pP[g];
      P[g].x = __builtin_amdgcn_exp2f(s.x);  // v_exp_f32
      P[g].y = __builtin_amdgcn_exp2f(s.y);
    }
    kkp[0] = kk0;
    kkp[1] = kk1;
    kkp[2] = kk2;
    kkp[3] = kk3;
#pragma unroll
    for (int g = 0; g < QPT; ++g) pP[g] = P[g];
  }

  // ---- pipeline epilogue: drain the last iteration's P ----
#pragma unroll
  for (int g = 0; g < QPT; ++g) {
    acc[g][0] = pkfma(pP[g], kkp[0], acc[g][0]);
    acc[g][1] = pkfma(pP[g], kkp[1], acc[g][1]);
    acc[g][2] = pkfma(pP[g], kkp[2], acc[g][2]);
    acc[g][3] = pkfma(pP[g], kkp[3], acc[g][3]);
    den[g] = den[g] + pP[g];
  }

#pragma unroll
  for (int g = 0; g < QPT; ++g) {
    const int q = qbase + 256 * g;
    if (FUSED) {
      const float i0 = 1.0f / den[g].x, i1 = 1.0f / den[g].y;
      float m[8] = {acc[g][0].x * i0, acc[g][1].x * i0, acc[g][2].x * i0,
                    acc[g][3].x * i0, acc[g][0].y * i1, acc[g][1].y * i1,
                    acc[g][2].y * i1, acc[g][3].y * i1};
      float o[8];
#pragma unroll
      for (int e = 0; e < 8; ++e) {
        float s = 0.f;
#pragma unroll
        for (int f = 0; f < 8; ++f) s += m[f] * Wout[e * 8 + f];
        o[e] = s;
      }
      float4* op = (float4*)(outp + ((size_t)b * NS + q) * 8);
      op[0] = make_float4(o[0], o[1], o[2], o[3]);
      op[1] = make_float4(o[4], o[5], o[6], o[7]);
    } else {
      // partial layout: [slice][component(10)][B*S]  (coalesced stores)
      const int idx = b * NS + q;
      float* p = outp + (size_t)slice * 10 * (NB * NS) + idx;
      p[0 * (NB * NS)] = acc[g][0].x;
      p[1 * (NB * NS)] = acc[g][1].x;
      p[2 * (NB * NS)] = acc[g][2].x;
      p[3 * (NB * NS)] = acc[g][3].x;
      p[4 * (NB * NS)] = acc[g][0].y;
      p[5 * (NB * NS)] = acc[g][1].y;
      p[6 * (NB * NS)] = acc[g][2].y;
      p[7 * (NB * NS)] = acc[g][3].y;
      p[8 * (NB * NS)] = den[g].x;
      p[9 * (NB * NS)] = den[g].y;
    }
  }
}

// ---------------------------------------------------------------------------
// Kernel B: sum slice partials, normalize, apply W_out^T, write out.
// ---------------------------------------------------------------------------
__global__ __launch_bounds__(256) void attn_reduce_kernel(
    const float* __restrict__ part, const float* __restrict__ Wout,
    float* __restrict__ out, int nslice) {
  const int idx = blockIdx.x * 256 + threadIdx.x;  // 0 .. B*S-1
  float a[10];
#pragma unroll
  for (int c = 0; c < 10; ++c) a[c] = 0.f;
  for (int sl = 0; sl < nslice; ++sl) {
    const float* p = part + (size_t)sl * 10 * (NB * NS) + idx;
#pragma unroll
    for (int c = 0; c < 10; ++c) a[c] += p[c * (NB * NS)];
  }
  const float i0 = 1.0f / a[8], i1 = 1.0f / a[9];
  float m[8] = {a[0] * i0, a[1] * i0, a[2] * i0, a[3] * i0,
                a[4] * i1, a[5] * i1, a[6] * i1, a[7] * i1};
  float o[8];
#pragma unroll
  for (int e = 0; e < 8; ++e) {
    float s = 0.f;
#pragma unroll
    for (int f = 0; f < 8; ++f) s += m[f] * Wout[e * 8 + f];
    o[e] = s;
  }
  float4* op = (float4*)(out + (size_t)idx * 8);
  op[0] = make_float4(o[0], o[1], o[2], o[3]);
  op[1] = make_float4(o[4], o[5], o[6], o[7]);
}

extern "C" void kernel_launch(void* const* d_in, const int* in_sizes, int n_in,
                              void* d_out, int out_size, void* d_ws,
                              size_t ws_size, hipStream_t stream) {
  const float* x = (const float*)d_in[0];      // [32, 2048, 8]
  const float* theta = (const float*)d_in[1];  // [8]
  const float* W = (const float*)d_in[2];      // [8, 8]
  float* out = (float*)d_out;                  // [32, 2048, 8]
  float* ws = (float*)d_ws;

  const size_t per_slice = (size_t)NB * NS * 10 * sizeof(float);  // 2.62 MB

  if (ws_size >= 8 * per_slice) {
    // 8-way split-K, 4 queries/thread: 512 blocks = 2/CU, 8 waves/CU.
    attn_part_kernel<256, 4, false>
        <<<dim3(NS / 1024, 8, NB), 256, 0, stream>>>(x, theta, W, ws);
    attn_reduce_kernel<<<(NB * NS) / 256, 256, 0, stream>>>(ws, W, out, 8);
  } else if (ws_size >= 4 * per_slice) {
    attn_part_kernel<512, 4, false>
        <<<dim3(NS / 1024, 4, NB), 256, 0, stream>>>(x, theta, W, ws);
    attn_reduce_kernel<<<(NB * NS) / 256, 256, 0, stream>>>(ws, W, out, 4);
  } else if (ws_size >= 2 * per_slice) {
    attn_part_kernel<1024, 4, false>
        <<<dim3(NS / 1024, 2, NB), 256, 0, stream>>>(x, theta, W, ws);
    attn_reduce_kernel<<<(NB * NS) / 256, 256, 0, stream>>>(ws, W, out, 2);
  } else {
    // Fused single-pass fallback (64 KB LDS, no workspace needed).
    attn_part_kernel<2048, 2, true>
        <<<dim3(NS / 512, 1, NB), 256, 0, stream>>>(x, theta, W, out);
  }
}

// Round 9
// 116.196 us; speedup vs baseline: 2.0659x; 1.1050x over previous
//
#include <hip/hip_runtime.h>

#define NB 32
#define NS 2048
// softmax scale 1/sqrt(d_k)=0.5 folded with log2(e) so we can use v_exp_f32 (2^x)
#define QSCALE 0.72134752044448170367f

typedef float v2f __attribute__((ext_vector_type(2)));
typedef float v4f __attribute__((ext_vector_type(4)));

// Packed f32 math via native vector ops -> LLVM selects v_pk_{mul,fma,add}_f32
// on gfx90a+ with correct op_sel/op_sel_hi.
__device__ __forceinline__ v2f pkfma(v2f a, v2f b, v2f c) {
  return __builtin_elementwise_fma(a, b, c);
}

// ---------------------------------------------------------------------------
// Fully-fused attention: BLOCK-LOCAL split-K, no workspace, no 2nd kernel.
//   - block = 256 threads = 4 waves; block owns 128 q-rows (QPT=2 per lane).
//   - wave w processes k-quarter w (512 of 2048 k-rows) -> 2048 waves total,
//     8 waves/CU, 2/SIMD (the R7-proven regime).
//   - k staged in 4 chunks of 512 rows (128 per quarter) = 16 KB LDS,
//     head-interleaved (k0,k4,k1,k5)(k2,k6,k3,k7) so both heads ride lo/hi
//     halves of v_pk_* ops. Wave LDS reads remain single-address broadcasts.
//   - scores bounded in [-2,2] (h = cos(..)) -> single-pass exp, no max.
//   - merge: waves 1-3 dump 20 partial floats via LDS (stride 21 =
//     conflict-free), wave 0 sums, normalizes, projects with W_out, stores.
// ---------------------------------------------------------------------------
__global__ __launch_bounds__(256, 2) void attn_fused_kernel(
    const float* __restrict__ x, const float* __restrict__ theta,
    const float* __restrict__ Wout, float* __restrict__ outp) {
  // 512 rows x 8 floats = 16 KB; reused as the merge buffer at the end.
  __shared__ __align__(16) float kv[512 * 8];

  const int b = blockIdx.y;
  const int t = threadIdx.x;
  const int w = t >> 6;    // wave index == k-quarter
  const int lane = t & 63;
  const int qbase = blockIdx.x * 128;

  float th[8];
#pragma unroll
  for (int e = 0; e < 8; ++e) th[e] = theta[e];

  // This lane's 2 query rows as head-interleaved pairs, pre-scaled.
  v2f qp[2][4];
#pragma unroll
  for (int g = 0; g < 2; ++g) {
    const float4* xq =
        (const float4*)(x + ((size_t)b * NS + qbase + 64 * g + lane) * 8);
    float4 lo = xq[0], hi = xq[1];
    qp[g][0] = (v2f){__cosf(lo.x + th[0]) * QSCALE, __cosf(hi.x + th[4]) * QSCALE};
    qp[g][1] = (v2f){__cosf(lo.y + th[1]) * QSCALE, __cosf(hi.y + th[5]) * QSCALE};
    qp[g][2] = (v2f){__cosf(lo.z + th[2]) * QSCALE, __cosf(hi.z + th[6]) * QSCALE};
    qp[g][3] = (v2f){__cosf(lo.w + th[3]) * QSCALE, __cosf(hi.w + th[7]) * QSCALE};
  }

  v2f acc[2][4];  // acc[g][i] = (sum p0*k_i, sum p1*k_{4+i})
  v2f den[2];     // (sum p0, sum p1)
#pragma unroll
  for (int g = 0; g < 2; ++g) {
    acc[g][0] = (v2f){0.f, 0.f};
    acc[g][1] = (v2f){0.f, 0.f};
    acc[g][2] = (v2f){0.f, 0.f};
    acc[g][3] = (v2f){0.f, 0.f};
    den[g] = (v2f){0.f, 0.f};
  }

  // ---- k-chunk loop: stage 512 rows (128 per quarter), then compute ----
  for (int c = 0; c < 4; ++c) {
    if (c) __syncthreads();  // previous chunk fully consumed before restage
    for (int l = t; l < 512; l += 256) {
      const int qtr = l >> 7;          // which quarter this LDS row belongs to
      const int rr = l & 127;          // row within the quarter's chunk
      const int gk = qtr * 512 + c * 128 + rr;
      const float4* xr = (const float4*)(x + ((size_t)b * NS + gk) * 8);
      float4 lo = xr[0], hi = xr[1];
      lo.x = __cosf(lo.x + th[0]);
      lo.y = __cosf(lo.y + th[1]);
      lo.z = __cosf(lo.z + th[2]);
      lo.w = __cosf(lo.w + th[3]);
      hi.x = __cosf(hi.x + th[4]);
      hi.y = __cosf(hi.y + th[5]);
      hi.z = __cosf(hi.z + th[6]);
      hi.w = __cosf(hi.w + th[7]);
      ((float4*)kv)[2 * l] = make_float4(lo.x, hi.x, lo.y, hi.y);
      ((float4*)kv)[2 * l + 1] = make_float4(lo.z, hi.z, lo.w, hi.w);
    }
    __syncthreads();

    // wave w's 128 rows start at float offset w*128*8 = v4f offset w*256
    const v4f* kp = (const v4f*)kv + (size_t)w * 256;
#pragma unroll 4
    for (int j = 0; j < 128; ++j) {
      // single-address broadcast per wave -> conflict-free b128 x2
      v4f A = kp[2 * j];
      v4f Bv = kp[2 * j + 1];
      v2f kk0 = A.xy;   // (k0, k4)
      v2f kk1 = A.zw;   // (k1, k5)
      v2f kk2 = Bv.xy;  // (k2, k6)
      v2f kk3 = Bv.zw;  // (k3, k7)
#pragma unroll
      for (int g = 0; g < 2; ++g) {
        v2f s = qp[g][0] * kk0;
        s = pkfma(qp[g][1], kk1, s);
        s = pkfma(qp[g][2], kk2, s);
        s = pkfma(qp[g][3], kk3, s);
        v2f P;
        P.x = __builtin_amdgcn_exp2f(s.x);  // v_exp_f32
        P.y = __builtin_amdgcn_exp2f(s.y);
        acc[g][0] = pkfma(P, kk0, acc[g][0]);
        acc[g][1] = pkfma(P, kk1, acc[g][1]);
        acc[g][2] = pkfma(P, kk2, acc[g][2]);
        acc[g][3] = pkfma(P, kk3, acc[g][3]);
        den[g] = den[g] + P;
      }
    }
  }

  // ---- block-local split-K merge through LDS ----
  __syncthreads();  // all waves done reading kv as k-tiles
  if (w > 0) {
    // stride 21 floats per lane: gcd(21,32)=1 -> no systematic bank conflict
    float* mb = kv + ((size_t)(w - 1) * 64 + lane) * 21;
#pragma unroll
    for (int g = 0; g < 2; ++g) {
      mb[10 * g + 0] = acc[g][0].x;
      mb[10 * g + 1] = acc[g][0].y;
      mb[10 * g + 2] = acc[g][1].x;
      mb[10 * g + 3] = acc[g][1].y;
      mb[10 * g + 4] = acc[g][2].x;
      mb[10 * g + 5] = acc[g][2].y;
      mb[10 * g + 6] = acc[g][3].x;
      mb[10 * g + 7] = acc[g][3].y;
      mb[10 * g + 8] = den[g].x;
      mb[10 * g + 9] = den[g].y;
    }
  }
  __syncthreads();
  if (w == 0) {
#pragma unroll
    for (int m = 0; m < 3; ++m) {
      const float* mb = kv + ((size_t)m * 64 + lane) * 21;
#pragma unroll
      for (int g = 0; g < 2; ++g) {
        acc[g][0].x += mb[10 * g + 0];
        acc[g][0].y += mb[10 * g + 1];
        acc[g][1].x += mb[10 * g + 2];
        acc[g][1].y += mb[10 * g + 3];
        acc[g][2].x += mb[10 * g + 4];
        acc[g][2].y += mb[10 * g + 5];
        acc[g][3].x += mb[10 * g + 6];
        acc[g][3].y += mb[10 * g + 7];
        den[g].x += mb[10 * g + 8];
        den[g].y += mb[10 * g + 9];
      }
    }
    // normalize + project (out = m @ W_out^T) + store
#pragma unroll
    for (int g = 0; g < 2; ++g) {
      const int q = qbase + 64 * g + lane;
      const float i0 = 1.0f / den[g].x, i1 = 1.0f / den[g].y;
      float m8[8] = {acc[g][0].x * i0, acc[g][1].x * i0, acc[g][2].x * i0,
                     acc[g][3].x * i0, acc[g][0].y * i1, acc[g][1].y * i1,
                     acc[g][2].y * i1, acc[g][3].y * i1};
      float o[8];
#pragma unroll
      for (int e = 0; e < 8; ++e) {
        float s = 0.f;
#pragma unroll
        for (int f = 0; f < 8; ++f) s += m8[f] * Wout[e * 8 + f];
        o[e] = s;
      }
      float4* op = (float4*)(outp + ((size_t)b * NS + q) * 8);
      op[0] = make_float4(o[0], o[1], o[2], o[3]);
      op[1] = make_float4(o[4], o[5], o[6], o[7]);
    }
  }
}

extern "C" void kernel_launch(void* const* d_in, const int* in_sizes, int n_in,
                              void* d_out, int out_size, void* d_ws,
                              size_t ws_size, hipStream_t stream) {
  const float* x = (const float*)d_in[0];      // [32, 2048, 8]
  const float* theta = (const float*)d_in[1];  // [8]
  const float* W = (const float*)d_in[2];      // [8, 8]
  float* out = (float*)d_out;                  // [32, 2048, 8]
  (void)d_ws;
  (void)ws_size;

  // 512 blocks (16 q-chunks x 32 batches) = 2 blocks/CU, 8 waves/CU.
  attn_fused_kernel<<<dim3(NS / 128, NB), 256, 0, stream>>>(x, theta, W, out);
}

// Round 10
// 115.845 us; speedup vs baseline: 2.0722x; 1.0030x over previous
//
#include <hip/hip_runtime.h>

#define NB 32
#define NS 2048
// softmax scale 1/sqrt(d_k)=0.5 folded with log2(e) so we can use v_exp_f32 (2^x)
#define QSCALE 0.72134752044448170367f

typedef float v2f __attribute__((ext_vector_type(2)));
typedef float v4f __attribute__((ext_vector_type(4)));

// Packed f32 math via native vector ops -> LLVM selects v_pk_{mul,fma,add}_f32
// on gfx90a+ with correct op_sel/op_sel_hi.
__device__ __forceinline__ v2f pkfma(v2f a, v2f b, v2f c) {
  return __builtin_elementwise_fma(a, b, c);
}

// ---------------------------------------------------------------------------
// Fully-fused attention: BLOCK-LOCAL split-K, no workspace, no 2nd kernel.
//   - block = 256 threads = 4 waves; block owns 128 q-rows (QPT=2 per lane).
//   - wave w processes k-quarter w (512 of 2048 k-rows).
//   - k staged in 2 chunks of 1024 rows (256 per quarter) = 32 KB LDS
//     (5 barriers total vs 9 with 4x512), head-interleaved
//     (k0,k4,k1,k5)(k2,k6,k3,k7) so both heads ride lo/hi halves of v_pk_*.
//     Wave LDS reads are single-address broadcasts (conflict-free).
//   - chunk 1's global loads are PREFETCHED into registers before chunk 0's
//     compute loop, so the mid-kernel restage is cos+ds_write only (no
//     exposed HBM/L2 latency between barriers).
//   - scores bounded in [-2,2] (h = cos(..)) -> single-pass exp, no max.
//   - merge: waves 1-3 dump 20 partial floats via LDS (stride 21, gcd(21,32)
//     =1 -> conflict-free), wave 0 sums, normalizes, projects W_out, stores.
// ---------------------------------------------------------------------------
__global__ __launch_bounds__(256, 2) void attn_fused_kernel(
    const float* __restrict__ x, const float* __restrict__ theta,
    const float* __restrict__ Wout, float* __restrict__ outp) {
  // 1024 rows x 8 floats = 32 KB; reused as the merge buffer at the end.
  __shared__ __align__(16) float kv[1024 * 8];

  const int b = blockIdx.y;
  const int t = threadIdx.x;
  const int w = t >> 6;    // wave index == k-quarter
  const int lane = t & 63;
  const int qbase = blockIdx.x * 128;

  float th[8];
#pragma unroll
  for (int e = 0; e < 8; ++e) th[e] = theta[e];

  // ---- stage chunk 0 (1024 rows; 256 per quarter) ----
  // thread handles rows l = t + 256*i; qtr = l>>8, rr = l&255
#pragma unroll
  for (int i = 0; i < 4; ++i) {
    const int l = t + 256 * i;
    const int qtr = l >> 8;
    const int rr = l & 255;
    const int gk = qtr * 512 + rr;  // chunk 0
    const float4* xr = (const float4*)(x + ((size_t)b * NS + gk) * 8);
    float4 lo = xr[0], hi = xr[1];
    lo.x = __cosf(lo.x + th[0]);
    lo.y = __cosf(lo.y + th[1]);
    lo.z = __cosf(lo.z + th[2]);
    lo.w = __cosf(lo.w + th[3]);
    hi.x = __cosf(hi.x + th[4]);
    hi.y = __cosf(hi.y + th[5]);
    hi.z = __cosf(hi.z + th[6]);
    hi.w = __cosf(hi.w + th[7]);
    ((float4*)kv)[2 * l] = make_float4(lo.x, hi.x, lo.y, hi.y);
    ((float4*)kv)[2 * l + 1] = make_float4(lo.z, hi.z, lo.w, hi.w);
  }

  // ---- prefetch chunk 1's raw x rows into registers (loads in flight
  //      across chunk 0's entire compute loop) ----
  float4 pf[4][2];
#pragma unroll
  for (int i = 0; i < 4; ++i) {
    const int l = t + 256 * i;
    const int qtr = l >> 8;
    const int rr = l & 255;
    const int gk = qtr * 512 + 256 + rr;  // chunk 1
    const float4* xr = (const float4*)(x + ((size_t)b * NS + gk) * 8);
    pf[i][0] = xr[0];
    pf[i][1] = xr[1];
  }

  // This lane's 2 query rows as head-interleaved pairs, pre-scaled.
  v2f qp[2][4];
#pragma unroll
  for (int g = 0; g < 2; ++g) {
    const float4* xq =
        (const float4*)(x + ((size_t)b * NS + qbase + 64 * g + lane) * 8);
    float4 lo = xq[0], hi = xq[1];
    qp[g][0] = (v2f){__cosf(lo.x + th[0]) * QSCALE, __cosf(hi.x + th[4]) * QSCALE};
    qp[g][1] = (v2f){__cosf(lo.y + th[1]) * QSCALE, __cosf(hi.y + th[5]) * QSCALE};
    qp[g][2] = (v2f){__cosf(lo.z + th[2]) * QSCALE, __cosf(hi.z + th[6]) * QSCALE};
    qp[g][3] = (v2f){__cosf(lo.w + th[3]) * QSCALE, __cosf(hi.w + th[7]) * QSCALE};
  }

  v2f acc[2][4];  // acc[g][i] = (sum p0*k_i, sum p1*k_{4+i})
  v2f den[2];     // (sum p0, sum p1)
#pragma unroll
  for (int g = 0; g < 2; ++g) {
    acc[g][0] = (v2f){0.f, 0.f};
    acc[g][1] = (v2f){0.f, 0.f};
    acc[g][2] = (v2f){0.f, 0.f};
    acc[g][3] = (v2f){0.f, 0.f};
    den[g] = (v2f){0.f, 0.f};
  }

  __syncthreads();  // (1) chunk 0 staged

  // ---- compute chunk 0: wave w reads LDS rows [w*256, w*256+256) ----
  {
    const v4f* kp = (const v4f*)kv + (size_t)w * 512;
#pragma unroll 4
    for (int j = 0; j < 256; ++j) {
      v4f A = kp[2 * j];
      v4f Bv = kp[2 * j + 1];
      v2f kk0 = A.xy, kk1 = A.zw, kk2 = Bv.xy, kk3 = Bv.zw;
#pragma unroll
      for (int g = 0; g < 2; ++g) {
        v2f s = qp[g][0] * kk0;
        s = pkfma(qp[g][1], kk1, s);
        s = pkfma(qp[g][2], kk2, s);
        s = pkfma(qp[g][3], kk3, s);
        v2f P;
        P.x = __builtin_amdgcn_exp2f(s.x);
        P.y = __builtin_amdgcn_exp2f(s.y);
        acc[g][0] = pkfma(P, kk0, acc[g][0]);
        acc[g][1] = pkfma(P, kk1, acc[g][1]);
        acc[g][2] = pkfma(P, kk2, acc[g][2]);
        acc[g][3] = pkfma(P, kk3, acc[g][3]);
        den[g] = den[g] + P;
      }
    }
  }

  __syncthreads();  // (2) chunk 0 fully consumed

  // ---- restage chunk 1 from prefetched registers (no memory latency) ----
#pragma unroll
  for (int i = 0; i < 4; ++i) {
    const int l = t + 256 * i;
    float4 lo = pf[i][0], hi = pf[i][1];
    lo.x = __cosf(lo.x + th[0]);
    lo.y = __cosf(lo.y + th[1]);
    lo.z = __cosf(lo.z + th[2]);
    lo.w = __cosf(lo.w + th[3]);
    hi.x = __cosf(hi.x + th[4]);
    hi.y = __cosf(hi.y + th[5]);
    hi.z = __cosf(hi.z + th[6]);
    hi.w = __cosf(hi.w + th[7]);
    ((float4*)kv)[2 * l] = make_float4(lo.x, hi.x, lo.y, hi.y);
    ((float4*)kv)[2 * l + 1] = make_float4(lo.z, hi.z, lo.w, hi.w);
  }

  __syncthreads();  // (3) chunk 1 staged

  // ---- compute chunk 1 ----
  {
    const v4f* kp = (const v4f*)kv + (size_t)w * 512;
#pragma unroll 4
    for (int j = 0; j < 256; ++j) {
      v4f A = kp[2 * j];
      v4f Bv = kp[2 * j + 1];
      v2f kk0 = A.xy, kk1 = A.zw, kk2 = Bv.xy, kk3 = Bv.zw;
#pragma unroll
      for (int g = 0; g < 2; ++g) {
        v2f s = qp[g][0] * kk0;
        s = pkfma(qp[g][1], kk1, s);
        s = pkfma(qp[g][2], kk2, s);
        s = pkfma(qp[g][3], kk3, s);
        v2f P;
        P.x = __builtin_amdgcn_exp2f(s.x);
        P.y = __builtin_amdgcn_exp2f(s.y);
        acc[g][0] = pkfma(P, kk0, acc[g][0]);
        acc[g][1] = pkfma(P, kk1, acc[g][1]);
        acc[g][2] = pkfma(P, kk2, acc[g][2]);
        acc[g][3] = pkfma(P, kk3, acc[g][3]);
        den[g] = den[g] + P;
      }
    }
  }

  // ---- block-local split-K merge through LDS ----
  __syncthreads();  // (4) all waves done reading kv as k-tiles
  if (w > 0) {
    // stride 21 floats per lane: gcd(21,32)=1 -> no systematic bank conflict
    float* mb = kv + ((size_t)(w - 1) * 64 + lane) * 21;
#pragma unroll
    for (int g = 0; g < 2; ++g) {
      mb[10 * g + 0] = acc[g][0].x;
      mb[10 * g + 1] = acc[g][0].y;
      mb[10 * g + 2] = acc[g][1].x;
      mb[10 * g + 3] = acc[g][1].y;
      mb[10 * g + 4] = acc[g][2].x;
      mb[10 * g + 5] = acc[g][2].y;
      mb[10 * g + 6] = acc[g][3].x;
      mb[10 * g + 7] = acc[g][3].y;
      mb[10 * g + 8] = den[g].x;
      mb[10 * g + 9] = den[g].y;
    }
  }
  __syncthreads();  // (5)
  if (w == 0) {
#pragma unroll
    for (int m = 0; m < 3; ++m) {
      const float* mb = kv + ((size_t)m * 64 + lane) * 21;
#pragma unroll
      for (int g = 0; g < 2; ++g) {
        acc[g][0].x += mb[10 * g + 0];
        acc[g][0].y += mb[10 * g + 1];
        acc[g][1].x += mb[10 * g + 2];
        acc[g][1].y += mb[10 * g + 3];
        acc[g][2].x += mb[10 * g + 4];
        acc[g][2].y += mb[10 * g + 5];
        acc[g][3].x += mb[10 * g + 6];
        acc[g][3].y += mb[10 * g + 7];
        den[g].x += mb[10 * g + 8];
        den[g].y += mb[10 * g + 9];
      }
    }
    // normalize + project (out = m @ W_out^T) + store
#pragma unroll
    for (int g = 0; g < 2; ++g) {
      const int q = qbase + 64 * g + lane;
      const float i0 = 1.0f / den[g].x, i1 = 1.0f / den[g].y;
      float m8[8] = {acc[g][0].x * i0, acc[g][1].x * i0, acc[g][2].x * i0,
                     acc[g][3].x * i0, acc[g][0].y * i1, acc[g][1].y * i1,
                     acc[g][2].y * i1, acc[g][3].y * i1};
      float o[8];
#pragma unroll
      for (int e = 0; e < 8; ++e) {
        float s = 0.f;
#pragma unroll
        for (int f = 0; f < 8; ++f) s += m8[f] * Wout[e * 8 + f];
        o[e] = s;
      }
      float4* op = (float4*)(outp + ((size_t)b * NS + q) * 8);
      op[0] = make_float4(o[0], o[1], o[2], o[3]);
      op[1] = make_float4(o[4], o[5], o[6], o[7]);
    }
  }
}

extern "C" void kernel_launch(void* const* d_in, const int* in_sizes, int n_in,
                              void* d_out, int out_size, void* d_ws,
                              size_t ws_size, hipStream_t stream) {
  const float* x = (const float*)d_in[0];      // [32, 2048, 8]
  const float* theta = (const float*)d_in[1];  // [8]
  const float* W = (const float*)d_in[2];      // [8, 8]
  float* out = (float*)d_out;                  // [32, 2048, 8]
  (void)d_ws;
  (void)ws_size;

  // 512 blocks (16 q-chunks x 32 batches) = 2 blocks/CU (32 KB LDS each),
  // 8 waves/CU.
  attn_fused_kernel<<<dim3(NS / 128, NB), 256, 0, stream>>>(x, theta, W, out);
}